// Round 5
// baseline (6281.119 us; speedup 1.0000x reference)
//
#include <hip/hip_runtime.h>

#define HD 64
#define L2E 1.4426950408889634f

__device__ __forceinline__ float fexp2(float x) { return __builtin_amdgcn_exp2f(x); }
__device__ __forceinline__ float frcp(float x)  { return __builtin_amdgcn_rcpf(x); }
__device__ __forceinline__ float ftanh_fast(float x) {
    return 1.f - 2.f * frcp(fexp2(2.f * L2E * x) + 1.f);
}

// 16x float4 dot into 4 accumulators (a0..a3, w[] in scope)
#define DOT16(HP) do { \
    _Pragma("unroll") \
    for (int q = 0; q < 16; ++q) { \
        float4 hv = (HP)[q]; \
        a0 = fmaf(w[4*q+0], hv.x, a0); \
        a1 = fmaf(w[4*q+1], hv.y, a1); \
        a2 = fmaf(w[4*q+2], hv.z, a2); \
        a3 = fmaf(w[4*q+3], hv.w, a3); \
    } } while (0)

// One workgroup (768 threads = 12 waves) per batch element — R2 structure:
//   A (waves 0-3):  layer-0 gates+update, t=i        (reads h0(i-1))
//   B (waves 4-7):  layer-1 xproj, t=i-1             (reads h0(i-1))
//   C (waves 8-11): layer-1 recurrent gates, t=i-2   (reads h1(i-3))
// NEW: h0/h1 are mirrored to a per-block global scratch buffer. Within each
// group, wave (w&3)==0 reads h from LDS; the other 3 read the global mirror —
// splitting broadcast traffic between the DS pipe and the (idle) VMEM pipe.
// Intra-block global RAW is ordered by __syncthreads (vmcnt drain + barrier,
// same CU, write-through L1). xbuf padded [4][80] for exact 2-way (free) banks.
__launch_bounds__(768, 3)
__global__ void lstm2_kernel(const float* __restrict__ x,     // [B,T]
                             const float* __restrict__ h0in,  // [2,B,HD]
                             const float* __restrict__ c0in,  // [2,B,HD]
                             const float* __restrict__ Wih0,  // [4H,1]
                             const float* __restrict__ Whh0,  // [4H,HD]
                             const float* __restrict__ bih0,
                             const float* __restrict__ bhh0,
                             const float* __restrict__ Wih1,  // [4H,HD]
                             const float* __restrict__ Whh1,  // [4H,HD]
                             const float* __restrict__ bih1,
                             const float* __restrict__ bhh1,
                             const float* __restrict__ Wlin,  // [1,HD]
                             const float* __restrict__ blin,  // [1]
                             float* __restrict__ hwsbase,     // [B*256] scratch
                             float* __restrict__ out,         // [B,T]
                             int B, int T)
{
    const int b    = blockIdx.x;
    const int tid  = threadIdx.x;
    const int wave = tid >> 6;
    const int lane = tid & 63;
    const int gg   = lane & 3;                      // gate: 0=i 1=f 2=g 3=o
    const int j    = (wave & 3) * 16 + (lane >> 2); // hidden unit (A/C layout)
    const int rA   = gg * HD + j;                   // quad-gate row (A, C)
    const int rB   = tid - 256;                     // natural row (B)

    const bool isA    = (wave < 4);
    const bool isB    = (wave >= 4 && wave < 8);
    const bool useLds = ((wave & 3) == 0);

    __shared__ float h0buf[2][HD];
    __shared__ float h1buf[2][HD];
    __shared__ float xbuf[2][4][80];     // [parity][gate][unit], +16 pad: 2-way free
    __shared__ __align__(16) float opart[2][4];

    // global mirror: [h0 p0 | h0 p1 | h1 p0 | h1 p1], 64 floats each
    float* hws = hwsbase + (size_t)b * 256;

    float w[HD];
    float bias = 0.f, wx0 = 0.f, cst = 0.f, wl = 0.f;

    // branchless activation: act = c1 + c2 * rcp(exp2(aa*x) + 1)
    const float aa = (gg == 2) ? 2.f * L2E : -L2E;
    const float c1 = (gg == 2) ? 1.f : 0.f;
    const float c2 = (gg == 2) ? -2.f : 1.f;

    if (isA) {
        const float4* wp = (const float4*)(Whh0 + rA * HD);
        #pragma unroll
        for (int q = 0; q < 16; ++q) {
            float4 v = wp[q];
            w[4*q] = v.x; w[4*q+1] = v.y; w[4*q+2] = v.z; w[4*q+3] = v.w;
        }
        bias = bih0[rA] + bhh0[rA];
        wx0  = Wih0[rA];
        if (gg == 0) cst = c0in[b * HD + j];
    } else if (isB) {
        const float4* wp = (const float4*)(Wih1 + rB * HD);
        #pragma unroll
        for (int q = 0; q < 16; ++q) {
            float4 v = wp[q];
            w[4*q] = v.x; w[4*q+1] = v.y; w[4*q+2] = v.z; w[4*q+3] = v.w;
        }
        bias = bih1[rB] + bhh1[rB];
    } else {
        const float4* wp = (const float4*)(Whh1 + rA * HD);
        #pragma unroll
        for (int q = 0; q < 16; ++q) {
            float4 v = wp[q];
            w[4*q] = v.x; w[4*q+1] = v.y; w[4*q+2] = v.z; w[4*q+3] = v.w;
        }
        if (gg == 0) cst = c0in[B * HD + b * HD + j];
        wl = Wlin[j];
    }

    if (tid < HD) {
        float v = h0in[b * HD + tid];
        h0buf[1][tid] = v;
        hws[64 + tid] = v;                 // h0 parity 1
    } else if (tid < 2 * HD) {
        float v = h0in[B * HD + b * HD + (tid - HD)];
        h1buf[1][tid - HD] = v;
        hws[192 + (tid - HD)] = v;         // h1 parity 1
    }

    const float blin0 = blin[0];
    float xchunk = 0.f;

    for (int i = 0; i <= T + 2; ++i) {
        __syncthreads();

        if (isA) {
            if (i < T) {                                   // layer 0, t = i
                if ((i & 63) == 0) {
                    int idx = i + lane; if (idx >= T) idx = T - 1;
                    xchunk = x[b * T + idx];
                }
                float xv = __shfl(xchunk, i & 63, 64);
                float a0 = fmaf(wx0, xv, bias), a1 = 0.f, a2 = 0.f, a3 = 0.f;
                if (useLds) {
                    const float4* hp = (const float4*)(h0buf[(i + 1) & 1]);
                    DOT16(hp);
                } else {
                    const float4* hp = (const float4*)(hws + ((i + 1) & 1) * 64);
                    DOT16(hp);
                }
                float acc = (a0 + a1) + (a2 + a3);
                float act = fmaf(c2, frcp(fexp2(acc * aa) + 1.f), c1);
                float v1 = __shfl_xor(act, 1, 64);
                float v2 = __shfl_xor(act, 2, 64);
                float v3 = __shfl_xor(act, 3, 64);
                // gg==0 lanes: v1=f, v2=g, v3=o, act=i
                cst = fmaf(v1, cst, act * v2);
                float h = v3 * ftanh_fast(cst);
                if (gg == 0) {
                    h0buf[i & 1][j] = h;
                    hws[(i & 1) * 64 + j] = h;
                }
            }
        } else if (isB) {
            if (i >= 1 && i <= T) {                        // layer-1 xproj, t = i-1
                float a0 = bias, a1 = 0.f, a2 = 0.f, a3 = 0.f;
                if (useLds) {
                    const float4* hp = (const float4*)(h0buf[(i + 1) & 1]);
                    DOT16(hp);
                } else {
                    const float4* hp = (const float4*)(hws + ((i + 1) & 1) * 64);
                    DOT16(hp);
                }
                xbuf[(i + 1) & 1][rB >> 6][rB & 63] = (a0 + a1) + (a2 + a3);
            }
        } else {
            if (i >= 2 && i <= T + 1) {                    // layer 1 recurrent, t = i-2
                float a0 = xbuf[i & 1][gg][j], a1 = 0.f, a2 = 0.f, a3 = 0.f;
                if (useLds) {
                    const float4* hp = (const float4*)(h1buf[(i + 1) & 1]);
                    DOT16(hp);
                } else {
                    const float4* hp = (const float4*)(hws + 128 + ((i + 1) & 1) * 64);
                    DOT16(hp);
                }
                float acc = (a0 + a1) + (a2 + a3);
                float act = fmaf(c2, frcp(fexp2(acc * aa) + 1.f), c1);
                float v1 = __shfl_xor(act, 1, 64);
                float v2 = __shfl_xor(act, 2, 64);
                float v3 = __shfl_xor(act, 3, 64);
                cst = fmaf(v1, cst, act * v2);
                float h = v3 * ftanh_fast(cst);
                if (gg == 0) {
                    h1buf[i & 1][j] = h;
                    hws[128 + (i & 1) * 64 + j] = h;
                }
                float p = (gg == 0) ? wl * h : 0.f;
                p += __shfl_xor(p, 4, 64);
                p += __shfl_xor(p, 8, 64);
                p += __shfl_xor(p, 16, 64);
                p += __shfl_xor(p, 32, 64);
                if (lane == 0) opart[i & 1][wave & 3] = p;
            }
        }

        if (tid == 256 && i >= 3) {                        // output store, t = i-3
            float4 op = *((const float4*)opart[(i + 1) & 1]);
            out[b * T + (i - 3)] = op.x + op.y + op.z + op.w + blin0;
        }
    }
}

extern "C" void kernel_launch(void* const* d_in, const int* in_sizes, int n_in,
                              void* d_out, int out_size, void* d_ws, size_t ws_size,
                              hipStream_t stream)
{
    const float* x    = (const float*)d_in[0];
    const float* h0   = (const float*)d_in[1];
    const float* c0   = (const float*)d_in[2];
    const float* Wih0 = (const float*)d_in[3];
    const float* Whh0 = (const float*)d_in[4];
    const float* bih0 = (const float*)d_in[5];
    const float* bhh0 = (const float*)d_in[6];
    const float* Wih1 = (const float*)d_in[7];
    const float* Whh1 = (const float*)d_in[8];
    const float* bih1 = (const float*)d_in[9];
    const float* bhh1 = (const float*)d_in[10];
    const float* Wlin = (const float*)d_in[11];
    const float* blin = (const float*)d_in[12];
    float* out = (float*)d_out;

    const int B = in_sizes[1] / (2 * HD);   // h0 is [2,B,HD]
    const int T = in_sizes[0] / B;          // input is [B,T]

    lstm2_kernel<<<dim3(B), dim3(768), 0, stream>>>(
        x, h0, c0, Wih0, Whh0, bih0, bhh0,
        Wih1, Whh1, bih1, bhh1, Wlin, blin,
        (float*)d_ws, out, B, T);
}

// Round 7
// 1584.816 us; speedup vs baseline: 3.9633x; 3.9633x over previous
//
#include <hip/hip_runtime.h>

#define HD 64
#define L2E 1.4426950408889634f

typedef _Float16 v2h __attribute__((ext_vector_type(2)));
typedef _Float16 h8  __attribute__((ext_vector_type(8)));

__device__ __forceinline__ float fexp2(float x) { return __builtin_amdgcn_exp2f(x); }
__device__ __forceinline__ float frcp(float x)  { return __builtin_amdgcn_rcpf(x); }
__device__ __forceinline__ float ftanh_fast(float x) {
    return 1.f - 2.f * frcp(fexp2(2.f * L2E * x) + 1.f);
}

#if __has_builtin(__builtin_amdgcn_fdot2)
__device__ __forceinline__ float FDOT2(v2h a, v2h b, float c) {
    return __builtin_amdgcn_fdot2(a, b, c, false);
}
#else
__device__ __forceinline__ float FDOT2(v2h a, v2h b, float c) {
    return fmaf((float)a.x, (float)b.x, fmaf((float)a.y, (float)b.y, c));
}
#endif

// f16 64-dot: 32x v_dot2_f32_f16 into 4 f32 accumulators. HP = h8* (8x b128).
#define DOTF16(HP) do { \
    _Pragma("unroll") \
    for (int q = 0; q < 8; ++q) { \
        h8 hv = (HP)[q]; \
        v2h p0 = {hv[0], hv[1]}, p1 = {hv[2], hv[3]}; \
        v2h p2 = {hv[4], hv[5]}, p3 = {hv[6], hv[7]}; \
        a0 = FDOT2(w2[4*q+0], p0, a0); \
        a1 = FDOT2(w2[4*q+1], p1, a1); \
        a2 = FDOT2(w2[4*q+2], p2, a2); \
        a3 = FDOT2(w2[4*q+3], p3, a3); \
    } } while (0)

// One workgroup (768 threads = 12 waves) per batch element — the R2/R5
// determinism-validated structure, with f16 weights + f16 h broadcasts:
//   A (waves 0-3):  layer-0 gates+update, t=i        (reads h0(i-1))
//   B (waves 4-7):  layer-1 xproj, t=i-1             (reads h0(i-1))
//   C (waves 8-11): layer-1 recurrent gates, t=i-2   (reads h1(i-3))
// h0/h1 stored in LDS as f16 (8 ds_read_b128 per wave instead of 16).
// Dots via v_dot2_f32_f16, f32 accumulate; c-state f32 in registers; output
// head uses in-register f32 h. ONE barrier/iter; parity double buffers,
// deps >=1 iter apart. All LDS zero-initialized pre-loop (launch-history
// independence insurance). xbuf stride 80 -> exact 2-way banks (free).
__launch_bounds__(768, 3)
__global__ void lstm2_kernel(const float* __restrict__ x,     // [B,T]
                             const float* __restrict__ h0in,  // [2,B,HD]
                             const float* __restrict__ c0in,  // [2,B,HD]
                             const float* __restrict__ Wih0,  // [4H,1]
                             const float* __restrict__ Whh0,  // [4H,HD]
                             const float* __restrict__ bih0,
                             const float* __restrict__ bhh0,
                             const float* __restrict__ Wih1,  // [4H,HD]
                             const float* __restrict__ Whh1,  // [4H,HD]
                             const float* __restrict__ bih1,
                             const float* __restrict__ bhh1,
                             const float* __restrict__ Wlin,  // [1,HD]
                             const float* __restrict__ blin,  // [1]
                             float* __restrict__ out,         // [B,T]
                             int B, int T)
{
    const int b    = blockIdx.x;
    const int tid  = threadIdx.x;
    const int wave = tid >> 6;
    const int lane = tid & 63;
    const int gg   = lane & 3;                      // gate: 0=i 1=f 2=g 3=o
    const int j    = (wave & 3) * 16 + (lane >> 2); // hidden unit (A/C layout)
    const int rA   = gg * HD + j;                   // quad-gate row (A, C)
    const int rB   = tid - 256;                     // natural row (B)

    const bool isA = (wave < 4);
    const bool isB = (wave >= 4 && wave < 8);

    __shared__ __align__(16) _Float16 h0buf[2][HD];
    __shared__ __align__(16) _Float16 h1buf[2][HD];
    __shared__ float xbuf[2][4][80];     // [parity][gate][unit], stride 80
    __shared__ __align__(16) float opart[2][4];

    // ---- zero-init ALL LDS (launch-history independence), then barrier ----
    {
        if (tid < 128) { h0buf[tid >> 6][tid & 63] = (_Float16)0.f;
                         h1buf[tid >> 6][tid & 63] = (_Float16)0.f; }
        float* xb = &xbuf[0][0][0];
        for (int idx = tid; idx < 2 * 4 * 80; idx += 768) xb[idx] = 0.f;
        if (tid < 8) opart[tid >> 2][tid & 3] = 0.f;
    }
    __syncthreads();

    v2h w2[32];                          // this wave's f16 weight row (64 elems)
    float bias = 0.f, wx0 = 0.f, cst = 0.f, wl = 0.f;

    // branchless activation: act = c1 + c2 * rcp(exp2(aa*x) + 1)
    const float aa = (gg == 2) ? 2.f * L2E : -L2E;
    const float c1 = (gg == 2) ? 1.f : 0.f;
    const float c2 = (gg == 2) ? -2.f : 1.f;

    if (isA) {
        const float4* wp = (const float4*)(Whh0 + rA * HD);
        #pragma unroll
        for (int q = 0; q < 16; ++q) {
            float4 v = wp[q];
            w2[2*q]   = v2h{(_Float16)v.x, (_Float16)v.y};
            w2[2*q+1] = v2h{(_Float16)v.z, (_Float16)v.w};
        }
        bias = bih0[rA] + bhh0[rA];
        wx0  = Wih0[rA];
        if (gg == 0) cst = c0in[b * HD + j];
    } else if (isB) {
        const float4* wp = (const float4*)(Wih1 + rB * HD);
        #pragma unroll
        for (int q = 0; q < 16; ++q) {
            float4 v = wp[q];
            w2[2*q]   = v2h{(_Float16)v.x, (_Float16)v.y};
            w2[2*q+1] = v2h{(_Float16)v.z, (_Float16)v.w};
        }
        bias = bih1[rB] + bhh1[rB];
    } else {
        const float4* wp = (const float4*)(Whh1 + rA * HD);
        #pragma unroll
        for (int q = 0; q < 16; ++q) {
            float4 v = wp[q];
            w2[2*q]   = v2h{(_Float16)v.x, (_Float16)v.y};
            w2[2*q+1] = v2h{(_Float16)v.z, (_Float16)v.w};
        }
        if (gg == 0) cst = c0in[B * HD + b * HD + j];
        wl = Wlin[j];
    }

    if (tid < HD)            h0buf[1][tid]      = (_Float16)h0in[b * HD + tid];
    else if (tid < 2 * HD)   h1buf[1][tid - HD] = (_Float16)h0in[B * HD + b * HD + (tid - HD)];

    const float blin0 = blin[0];
    float xchunk = 0.f;

    for (int i = 0; i <= T + 2; ++i) {
        __syncthreads();

        if (isA) {
            if (i < T) {                                   // layer 0, t = i
                if ((i & 63) == 0) {
                    int idx = i + lane; if (idx >= T) idx = T - 1;
                    xchunk = x[b * T + idx];
                }
                float xv = __shfl(xchunk, i & 63, 64);
                const h8* hp = (const h8*)(h0buf[(i + 1) & 1]);
                float a0 = fmaf(wx0, xv, bias), a1 = 0.f, a2 = 0.f, a3 = 0.f;
                DOTF16(hp);
                float acc = (a0 + a1) + (a2 + a3);
                float act = fmaf(c2, frcp(fexp2(acc * aa) + 1.f), c1);
                float v1 = __shfl_xor(act, 1, 64);
                float v2 = __shfl_xor(act, 2, 64);
                float v3 = __shfl_xor(act, 3, 64);
                // gg==0 lanes: act=i, v1=f, v2=g, v3=o
                cst = fmaf(v1, cst, act * v2);
                float h = v3 * ftanh_fast(cst);
                if (gg == 0) h0buf[i & 1][j] = (_Float16)h;
            }
        } else if (isB) {
            if (i >= 1 && i <= T) {                        // layer-1 xproj, t = i-1
                const h8* hp = (const h8*)(h0buf[(i + 1) & 1]);
                float a0 = bias, a1 = 0.f, a2 = 0.f, a3 = 0.f;
                DOTF16(hp);
                xbuf[(i + 1) & 1][rB >> 6][rB & 63] = (a0 + a1) + (a2 + a3);
            }
        } else {
            if (i >= 2 && i <= T + 1) {                    // layer 1 recurrent, t = i-2
                const h8* hp = (const h8*)(h1buf[(i + 1) & 1]);
                float a0 = xbuf[i & 1][gg][j], a1 = 0.f, a2 = 0.f, a3 = 0.f;
                DOTF16(hp);
                float acc = (a0 + a1) + (a2 + a3);
                float act = fmaf(c2, frcp(fexp2(acc * aa) + 1.f), c1);
                float v1 = __shfl_xor(act, 1, 64);
                float v2 = __shfl_xor(act, 2, 64);
                float v3 = __shfl_xor(act, 3, 64);
                cst = fmaf(v1, cst, act * v2);
                float h = v3 * ftanh_fast(cst);
                if (gg == 0) h1buf[i & 1][j] = (_Float16)h;
                float p = (gg == 0) ? wl * h : 0.f;        // in-register f32 h
                p += __shfl_xor(p, 4, 64);
                p += __shfl_xor(p, 8, 64);
                p += __shfl_xor(p, 16, 64);
                p += __shfl_xor(p, 32, 64);
                if (lane == 0) opart[i & 1][wave & 3] = p;
            }
        }

        if (tid == 256 && i >= 3) {                        // output store, t = i-3
            float4 op = *((const float4*)opart[(i + 1) & 1]);
            out[b * T + (i - 3)] = op.x + op.y + op.z + op.w + blin0;
        }
    }
}

extern "C" void kernel_launch(void* const* d_in, const int* in_sizes, int n_in,
                              void* d_out, int out_size, void* d_ws, size_t ws_size,
                              hipStream_t stream)
{
    const float* x    = (const float*)d_in[0];
    const float* h0   = (const float*)d_in[1];
    const float* c0   = (const float*)d_in[2];
    const float* Wih0 = (const float*)d_in[3];
    const float* Whh0 = (const float*)d_in[4];
    const float* bih0 = (const float*)d_in[5];
    const float* bhh0 = (const float*)d_in[6];
    const float* Wih1 = (const float*)d_in[7];
    const float* Whh1 = (const float*)d_in[8];
    const float* bih1 = (const float*)d_in[9];
    const float* bhh1 = (const float*)d_in[10];
    const float* Wlin = (const float*)d_in[11];
    const float* blin = (const float*)d_in[12];
    float* out = (float*)d_out;

    const int B = in_sizes[1] / (2 * HD);   // h0 is [2,B,HD]
    const int T = in_sizes[0] / B;          // input is [B,T]

    lstm2_kernel<<<dim3(B), dim3(768), 0, stream>>>(
        x, h0, c0, Wih0, Whh0, bih0, bhh0,
        Wih1, Whh1, bih1, bhh1, Wlin, blin, out, B, T);
}